// Round 15
// baseline (30.871 us; speedup 1.0000x reference)
//
#include <hip/hip_runtime.h>
#include <hip/hip_fp16.h>

// Local attention block: 40^3 volume, C=64, 4 heads of hd=16, 3x3x3 window,
// replicate padding, residual add. f32 in/out.
//
// All intermediates FP16. QKV head-planar [head][N][16ch] (dense 32 B/voxel
// runs per head-block; round-14 win).
// Kernel 1: proj via MFMA 16x16x32 f16 (round-13/14, unchanged). 500 blocks
//           x 512 threads; W f32->f16 LDS; x B-fragments direct to regs.
// Kernel 2: attention, block = (4x8x8 tile, ONE head), 256 threads: thread
//           = (x-adjacent VOXEL PAIR, 8ch part). The pair's 3-wide x-windows
//           overlap 2/3 -> 4 K + 4 V LDS reads serve 6 logits/PV steps:
//           LDS read traffic x0.67 (attn is ds_read-throughput bound:
//           27*64B*64000 = 442 MB at ~85 B/cy/CU was the 9.7 us floor).
//           DPP xor-1 pair reduce, packed-f16 hfma2, e/16 PV scaling.

#define NVOX 64000   // 40*40*40
#define DIM 40
#define CCH 64
#define HEADS 4
#define HD 16
#define HPL (NVOX * HD)   // head-plane stride in f16 elements

// attn tile geometry (one head per block)
#define ATZ 4
#define ATY 8
#define ATX 8
#define ANH 600           // 6*10*10 halo voxels

typedef __attribute__((ext_vector_type(8))) _Float16 f16x8;
typedef __attribute__((ext_vector_type(4))) float f32x4;

__device__ __forceinline__ unsigned pkh(float a, float b) {
    __half2 h = __floats2half2_rn(a, b);
    return *reinterpret_cast<unsigned*>(&h);
}
__device__ __forceinline__ __half2 u2h(unsigned u) {
    __half2 h; *reinterpret_cast<unsigned*>(&h) = u; return h;
}

__device__ __forceinline__ int xcd_swz(int b) {   // bijective, 1000 % 8 == 0
    return (b & 7) * 125 + (b >> 3);
}
__device__ __forceinline__ int xcd_swz500(int b) { // bijective for 500 (m204)
    const int xcd = b & 7, loc = b >> 3;           // q=62, r=4
    return (xcd < 4 ? xcd * 63 : 252 + (xcd - 4) * 62) + loc;
}

__device__ __forceinline__ float dot8(const __half2* q, uint4 k) {
    __half2 a = __hmul2(q[0], u2h(k.x));
    a = __hfma2(q[1], u2h(k.y), a);
    a = __hfma2(q[2], u2h(k.z), a);
    a = __hfma2(q[3], u2h(k.w), a);
    return __low2float(a) + __high2float(a);
}
__device__ __forceinline__ float pairsum(float v) {
    // DPP quad_perm [1,0,3,2]: swap with lane^1 (other part), pure VALU
    const int o = __builtin_amdgcn_mov_dpp(__float_as_int(v), 0xB1, 0xF, 0xF, true);
    return v + __int_as_float(o);
}

__global__ __launch_bounds__(512) void proj_mfma(
    const float* __restrict__ x,
    const float* __restrict__ Wq, const float* __restrict__ bq,
    const float* __restrict__ Wk, const float* __restrict__ bk,
    const float* __restrict__ Wv, const float* __restrict__ bv,
    unsigned short* __restrict__ Qg, unsigned short* __restrict__ Kg,
    unsigned short* __restrict__ Vg)
{
    // W LDS: [chunk(8ch)][192 rows][8 f16] -> 16 B lane stride (conflict-free)
    __shared__ __align__(16) unsigned short Wl[8 * 192 * 8];  // 24576 B
    __shared__ __align__(16) float bl[192];                   //   768 B

    const int tid = threadIdx.x;
    const int bid = xcd_swz500((int)blockIdx.x);
    const int n0 = bid * 128;                // 500 * 128 = 64000

    const int lane = tid & 63;
    const int wv   = tid >> 6;               // 8 waves -> 8 voxel-16-tiles
    const int l15  = lane & 15;
    const int l4   = lane >> 4;
    const int vox  = wv * 16 + l15;
    const int n    = n0 + vox;               // D col = lane&15 -> voxel

    // ---- x B-fragments direct to registers; issue BEFORE the W barrier ----
    float xf[16];
    #pragma unroll
    for (int j = 0; j < 8; ++j)
        xf[j] = x[(l4 * 8 + j) * NVOX + n];          // 64B-segment coalesced
    #pragma unroll
    for (int j = 0; j < 8; ++j)
        xf[8 + j] = x[(32 + l4 * 8 + j) * NVOX + n];

    // ---- Stage W + bias: 1536 items over 512 threads (3 each) ----
    #pragma unroll
    for (int i = 0; i < 3; ++i) {
        const int item = tid + i * 512;
        const int row = item % 192, chunk = item / 192;
        const float* Wsrc; float sc; int r;
        if (row < 64)       { Wsrc = Wq; sc = 0.25f; r = row; }
        else if (row < 128) { Wsrc = Wk; sc = 1.0f;  r = row - 64; }
        else                { Wsrc = Wv; sc = 1.0f;  r = row - 128; }
        const float4 f0 = *reinterpret_cast<const float4*>(&Wsrc[r * 64 + chunk * 8]);
        const float4 f1 = *reinterpret_cast<const float4*>(&Wsrc[r * 64 + chunk * 8 + 4]);
        *reinterpret_cast<uint4*>(&Wl[(chunk * 192 + row) * 8]) =
            make_uint4(pkh(sc * f0.x, sc * f0.y), pkh(sc * f0.z, sc * f0.w),
                       pkh(sc * f1.x, sc * f1.y), pkh(sc * f1.z, sc * f1.w));
    }
    if (tid < 192) {
        const float* bsrc; float sc; int r;
        if (tid < 64)       { bsrc = bq; sc = 0.25f; r = tid; }
        else if (tid < 128) { bsrc = bk; sc = 1.0f;  r = tid - 64; }
        else                { bsrc = bv; sc = 1.0f;  r = tid - 128; }
        bl[tid] = sc * bsrc[r];
    }

    // Pack x fragments while W loads are in flight.
    union { unsigned u[4]; f16x8 v; } U0, U1;
    #pragma unroll
    for (int p = 0; p < 4; ++p) {
        U0.u[p] = pkh(xf[2 * p], xf[2 * p + 1]);
        U1.u[p] = pkh(xf[8 + 2 * p], xf[9 + 2 * p]);
    }
    const f16x8 bx0 = U0.v, bx1 = U1.v;

    __syncthreads();

    #pragma unroll
    for (int rb = 0; rb < 12; ++rb) {
        const int row = rb * 16 + l15;       // A row, k-chunks l4 / l4+4
        const f16x8 a0 = *reinterpret_cast<const f16x8*>(&Wl[(l4 * 192 + row) * 8]);
        const f16x8 a1 = *reinterpret_cast<const f16x8*>(&Wl[((l4 + 4) * 192 + row) * 8]);

        f32x4 acc = {0.f, 0.f, 0.f, 0.f};
        acc = __builtin_amdgcn_mfma_f32_16x16x32_f16(a0, bx0, acc, 0, 0, 0);
        acc = __builtin_amdgcn_mfma_f32_16x16x32_f16(a1, bx1, acc, 0, 0, 0);

        const int r0 = rb * 16 + l4 * 4;     // D rows r0..r0+3 for this lane
        const float4 bs = *reinterpret_cast<const float4*>(&bl[r0]);

        // Head-planar store: matrix = rb>>2, head = rb&3, ch = l4*4.
        unsigned short* og = (rb < 4) ? Qg : (rb < 8) ? Kg : Vg;
        const size_t dst = (size_t)(rb & 3) * HPL + (size_t)n * HD + l4 * 4;
        *reinterpret_cast<uint2*>(&og[dst]) =
            make_uint2(pkh(acc[0] + bs.x, acc[1] + bs.y),
                       pkh(acc[2] + bs.z, acc[3] + bs.w));
    }
}

__global__ __launch_bounds__(256, 4) void attn_kernel(
    const float* __restrict__ x,
    const unsigned short* __restrict__ Qg, const unsigned short* __restrict__ Kg,
    const unsigned short* __restrict__ Vg,
    float* __restrict__ out)
{
    // LDS per matrix: [half(8ch)][600 halo voxels][8 f16] -> 16 B lane stride
    __shared__ __align__(16) unsigned short Kl[2 * ANH * 8];   // 19200 B
    __shared__ __align__(16) unsigned short Vl[2 * ANH * 8];   // 19200 B

    const int tid = threadIdx.x;
    const int bid = xcd_swz((int)blockIdx.x);   // 250 tiles x 4 heads
    const int h    = bid & 3;
    const int tile = bid >> 2;
    const int tx = tile % 5;
    const int ty = (tile / 5) % 5;
    const int tz = tile / 25;
    const int z0 = tz * ATZ - 1, y0 = ty * ATY - 1, x0 = tx * ATX - 1;

    const unsigned short* Qh = Qg + (size_t)h * HPL;
    const unsigned short* Kh = Kg + (size_t)h * HPL;
    const unsigned short* Vh = Vg + (size_t)h * HPL;

    // ---- Thread = (x-adjacent voxel pair, part) ----
    const int pr   = tid >> 1;            // 0..127 voxel-pair
    const int part = tid & 1;             // 0: ch 0-7, 1: ch 8-15
    const int lz  = pr >> 5;              // 0..3
    const int ly  = (pr >> 2) & 7;        // 0..7
    const int lx0 = (pr & 3) * 2;         // 0,2,4,6
    const int gz = tz * ATZ + lz, gy = ty * ATY + ly, gx = tx * ATX + lx0;
    const int n0v = (gz * DIM + gy) * DIM + gx;
    const int n1v = n0v + 1;              // x is the fastest dim

    // Q for both voxels (this part's 8 channels), issued before staging.
    const uint4 qw0 = *reinterpret_cast<const uint4*>(&Qh[(size_t)n0v * HD + part * 8]);
    const uint4 qw1 = *reinterpret_cast<const uint4*>(&Qh[(size_t)n1v * HD + part * 8]);

    // ---- Stage K+V halo: 600 items, 32 B of K + 32 B of V each (dense) ----
    #pragma unroll
    for (int i = 0; i < 3; ++i) {
        const int ml = tid + i * 256;
        if (ml < ANH) {
            const int hz = ml / 100; const int r = ml - hz * 100;
            const int hy = r / 10;   const int hx = r - hy * 10;
            const int sz = min(max(z0 + hz, 0), DIM - 1);
            const int sy = min(max(y0 + hy, 0), DIM - 1);
            const int sx = min(max(x0 + hx, 0), DIM - 1);
            const size_t base = (size_t)((sz * DIM + sy) * DIM + sx) * HD;
            const uint4 k0 = *reinterpret_cast<const uint4*>(&Kh[base]);
            const uint4 k1 = *reinterpret_cast<const uint4*>(&Kh[base + 8]);
            const uint4 v0 = *reinterpret_cast<const uint4*>(&Vh[base]);
            const uint4 v1 = *reinterpret_cast<const uint4*>(&Vh[base + 8]);
            *reinterpret_cast<uint4*>(&Kl[ml * 8])           = k0;
            *reinterpret_cast<uint4*>(&Kl[ANH * 8 + ml * 8]) = k1;
            *reinterpret_cast<uint4*>(&Vl[ml * 8])           = v0;
            *reinterpret_cast<uint4*>(&Vl[ANH * 8 + ml * 8]) = v1;
        }
    }
    __syncthreads();

    __half2 qh0[4], qh1[4];
    qh0[0] = u2h(qw0.x); qh0[1] = u2h(qw0.y); qh0[2] = u2h(qw0.z); qh0[3] = u2h(qw0.w);
    qh1[0] = u2h(qw1.x); qh1[1] = u2h(qw1.y); qh1[2] = u2h(qw1.z); qh1[3] = u2h(qw1.w);

    // Halo-local center of vox0; window columns are off-1 .. off+2.
    const int mlc = (lz + 1) * 100 + (ly + 1) * 10 + (lx0 + 1);
    const uint4* kb = reinterpret_cast<const uint4*>(Kl) + part * ANH + mlc;
    const uint4* vb = reinterpret_cast<const uint4*>(Vl) + part * ANH + mlc;

    float s0 = 0.0f, s1 = 0.0f;
    __half2 av0[4], av1[4];
    #pragma unroll
    for (int i = 0; i < 4; ++i) { av0[i] = __float2half2_rn(0.0f); av1[i] = av0[i]; }

    #pragma unroll
    for (int dz = -1; dz <= 1; ++dz) {
        #pragma unroll
        for (int dy = -1; dy <= 1; ++dy) {
            const int off = dz * 100 + dy * 10;
            // 4 shared K columns serve both voxels' 3-wide windows.
            const uint4 k0 = kb[off - 1];
            const uint4 k1 = kb[off];
            const uint4 k2 = kb[off + 1];
            const uint4 k3 = kb[off + 2];

            // max-free softmax: logits ~N(0,1); e^|lg| far from f32 limit
            const float e00 = __expf(pairsum(dot8(qh0, k0)));
            const float e01 = __expf(pairsum(dot8(qh0, k1)));
            const float e02 = __expf(pairsum(dot8(qh0, k2)));
            const float e10 = __expf(pairsum(dot8(qh1, k1)));
            const float e11 = __expf(pairsum(dot8(qh1, k2)));
            const float e12 = __expf(pairsum(dot8(qh1, k3)));
            s0 += e00 + e01 + e02;
            s1 += e10 + e11 + e12;

            const uint4 v0 = vb[off - 1];
            const uint4 v1 = vb[off];
            const uint4 v2 = vb[off + 1];
            const uint4 v3 = vb[off + 2];

            // accumulate with e/16: f16 headroom to logit ~13.9
            __half2 w;
            w = __float2half2_rn(e00 * 0.0625f);
            av0[0] = __hfma2(w, u2h(v0.x), av0[0]);
            av0[1] = __hfma2(w, u2h(v0.y), av0[1]);
            av0[2] = __hfma2(w, u2h(v0.z), av0[2]);
            av0[3] = __hfma2(w, u2h(v0.w), av0[3]);
            w = __float2half2_rn(e01 * 0.0625f);
            av0[0] = __hfma2(w, u2h(v1.x), av0[0]);
            av0[1] = __hfma2(w, u2h(v1.y), av0[1]);
            av0[2] = __hfma2(w, u2h(v1.z), av0[2]);
            av0[3] = __hfma2(w, u2h(v1.w), av0[3]);
            w = __float2half2_rn(e02 * 0.0625f);
            av0[0] = __hfma2(w, u2h(v2.x), av0[0]);
            av0[1] = __hfma2(w, u2h(v2.y), av0[1]);
            av0[2] = __hfma2(w, u2h(v2.z), av0[2]);
            av0[3] = __hfma2(w, u2h(v2.w), av0[3]);

            w = __float2half2_rn(e10 * 0.0625f);
            av1[0] = __hfma2(w, u2h(v1.x), av1[0]);
            av1[1] = __hfma2(w, u2h(v1.y), av1[1]);
            av1[2] = __hfma2(w, u2h(v1.z), av1[2]);
            av1[3] = __hfma2(w, u2h(v1.w), av1[3]);
            w = __float2half2_rn(e11 * 0.0625f);
            av1[0] = __hfma2(w, u2h(v2.x), av1[0]);
            av1[1] = __hfma2(w, u2h(v2.y), av1[1]);
            av1[2] = __hfma2(w, u2h(v2.z), av1[2]);
            av1[3] = __hfma2(w, u2h(v2.w), av1[3]);
            w = __float2half2_rn(e12 * 0.0625f);
            av1[0] = __hfma2(w, u2h(v3.x), av1[0]);
            av1[1] = __hfma2(w, u2h(v3.y), av1[1]);
            av1[2] = __hfma2(w, u2h(v3.z), av1[2]);
            av1[3] = __hfma2(w, u2h(v3.w), av1[3]);
        }
    }

    const float rs0 = 16.0f / s0;            // undo the 1/16 scaling
    const float rs1 = 16.0f / s1;
    const int cb = h * HD + part * 8;
    #pragma unroll
    for (int i = 0; i < 4; ++i) {
        const size_t c0 = (size_t)(cb + 2 * i) * NVOX;
        const size_t c1 = (size_t)(cb + 2 * i + 1) * NVOX;
        out[c0 + n0v] = x[c0 + n0v] + __low2float(av0[i])  * rs0;
        out[c1 + n0v] = x[c1 + n0v] + __high2float(av0[i]) * rs0;
        out[c0 + n1v] = x[c0 + n1v] + __low2float(av1[i])  * rs1;
        out[c1 + n1v] = x[c1 + n1v] + __high2float(av1[i]) * rs1;
    }
}

extern "C" void kernel_launch(void* const* d_in, const int* in_sizes, int n_in,
                              void* d_out, int out_size, void* d_ws, size_t ws_size,
                              hipStream_t stream) {
    const float* x  = (const float*)d_in[0];
    // d_in[1] = cemb (unused by the reference)
    const float* Wq = (const float*)d_in[2];
    const float* bq = (const float*)d_in[3];
    const float* Wk = (const float*)d_in[4];
    const float* bk = (const float*)d_in[5];
    const float* Wv = (const float*)d_in[6];
    const float* bv = (const float*)d_in[7];
    float* out = (float*)d_out;

    unsigned short* Qg = (unsigned short*)d_ws;        // f16 [4][N][16]
    unsigned short* Kg = Qg + (size_t)NVOX * CCH;      // f16 [4][N][16]
    unsigned short* Vg = Kg + (size_t)NVOX * CCH;      // f16 [4][N][16]

    proj_mfma<<<dim3(500), dim3(512), 0, stream>>>(
        x, Wq, bq, Wk, bk, Wv, bv, Qg, Kg, Vg);
    attn_kernel<<<dim3(1000), dim3(256), 0, stream>>>(
        x, Qg, Kg, Vg, out);
}